// Round 1
// baseline (458.434 us; speedup 1.0000x reference)
//
#include <hip/hip_runtime.h>

// x: (64, 512, 52, 52) fp32 -> out: (64, 512, 13, 13) fp32
// window 4x4 stride 4 sum, *1/32, round-half-even, clip [-128,127].
// Memory-bound: ~354 MB read + ~22 MB write, every input byte touched once.

#define PLANES   (64 * 512)
#define H        52
#define W        52
#define OH       13
#define OW       13
#define N_OUT    (PLANES * OH * OW)

__global__ __launch_bounds__(256) void pool_sum_round_kernel(
    const float* __restrict__ x, float* __restrict__ out) {
    int idx = blockIdx.x * blockDim.x + threadIdx.x;
    if (idx >= N_OUT) return;

    int ow    = idx % OW;
    int t     = idx / OW;
    int oh    = t % OH;
    int plane = t / OH;

    // Row base: plane*2704 + (oh*4)*52 + ow*4 floats. All float4-aligned:
    // plane stride 10816 B, row stride 208 B, col step 16 B.
    const float* base = x + (size_t)plane * (H * W) + (size_t)(oh * 4) * W + ow * 4;

    float s = 0.0f;
#pragma unroll
    for (int r = 0; r < 4; ++r) {
        float4 v = *reinterpret_cast<const float4*>(base + r * W);
        s += (v.x + v.y) + (v.z + v.w);
    }

    float o = rintf(s * 0.03125f);          // p = 1/(2*4*4), exact pow2 scale
    o = fminf(fmaxf(o, -128.0f), 127.0f);
    out[idx] = o;
}

extern "C" void kernel_launch(void* const* d_in, const int* in_sizes, int n_in,
                              void* d_out, int out_size, void* d_ws, size_t ws_size,
                              hipStream_t stream) {
    const float* x = (const float*)d_in[0];
    float* out = (float*)d_out;
    int blocks = (N_OUT + 255) / 256;
    pool_sum_round_kernel<<<blocks, 256, 0, stream>>>(x, out);
}